// Round 5
// baseline (268.825 us; speedup 1.0000x reference)
//
#include <hip/hip_runtime.h>
#include <stdint.h>

// Problem constants
#define B_   16
#define D_   256
#define T_   4096
#define K_   1024
#define N_   (B_ * T_)      // 65536 points
#define BM   64             // points per sub-tile; each block does TWO sub-tiles

typedef __attribute__((ext_vector_type(4))) float floatx4;
typedef __attribute__((ext_vector_type(2))) float floatx2;
typedef __attribute__((ext_vector_type(2))) long longx2;

// ---- Kernel 0: emb fp32 -> fp8 e4m3 (scaled x1024), stored in PIECE order:
// tile ct = codes [ct*16, ct*16+16), 4 KB = 4 pieces of 1 KB. Byte for
// (code c, dim d): ct=c>>4, ml=c&15, kk=d>>5, quad=(d>>3)&3, b=d&7 at
//   ct*4096 + (kk>>1)*1024 + (quad*16+ml)*16 + (kk&1)*8 + b
// esqh[c] = 1024*0.5*||e_exact||^2. Also zeroes loss.
__global__ __launch_bounds__(256) void emb_prep(const float* __restrict__ emb,
                                                uint32_t* __restrict__ embf8,
                                                float* __restrict__ esqh,
                                                float* __restrict__ lossp) {
    int w = threadIdx.x >> 6, lane = threadIdx.x & 63;
    int k = blockIdx.x * 4 + w;                       // one wave per code row
    float4 v = ((const float4*)emb)[k * 64 + lane];   // d0 = lane*4
    float a0 = v.x * 1024.f, a1 = v.y * 1024.f, a2 = v.z * 1024.f, a3 = v.w * 1024.f;
    int p = __builtin_amdgcn_cvt_pk_fp8_f32(a0, a1, 0, false);
    p = __builtin_amdgcn_cvt_pk_fp8_f32(a2, a3, p, true);
    int kk = lane >> 3, quad = (lane >> 1) & 3;       // from d0 = lane*4
    int widx = (k >> 4) * 1024 + (kk >> 1) * 256 + (quad * 16 + (k & 15)) * 4
             + (kk & 1) * 2 + (lane & 1);
    embf8[widx] = (uint32_t)p;
    float ss = a0 * a0 + a1 * a1 + a2 * a2 + a3 * a3;   // exact (pre-fp8) scaled norm
    #pragma unroll
    for (int off = 32; off; off >>= 1) ss += __shfl_xor(ss, off, 64);
    if (lane == 0) esqh[k] = ss * (0.5f / 1024.f);      // = 1024 * 0.5*||e||^2
    if (blockIdx.x == 0 && threadIdx.x == 0) *lossp = 0.f;
}

// ---- Main kernel (R5: 2-tile phase pipeline) ----
// R4 post-mortem: single generation made P1 (mem, ~25Kcy/CU) -> k-loop
// (MFMA, ~40Kcy) -> P4 (mem, ~25Kcy) a lockstep convoy; no pipe >33% busy.
// R5: each block processes TWO 64-point tiles (grid 512, 2 blocks/CU,
// launch_bounds(256,2) = 256-reg cap):
//   P1(A) -> [k-loop(A) || P1(B) chunks] -> argmin(A)
//        -> [k-loop(B) || P4(A) gather/transpose/store] -> argmin(B) -> P4(B)
// so tile B's HBM reads hide under tile A's MFMAs and tile A's HBM writes
// hide under tile B's MFMAs. Exposed serial memory: P1(A) + P4(B) only.
// Ordering inside the k-loop keeps qq prefetch ISSUED BEFORE the z/gather
// loads so counted vmcnt on qq never drains the slower HBM stream.
// Wave decomposition per tile (R4): wave w = point-half ph=w>>1 x code-half
// ch=w&1 (32 tiles x 16 MFMA, 4 chains via k-split lo/hi, eh folded into
// the lo-chain C operand; A holds NEGATED z fp8 so acc = eh - x.e).
// Argmin: packed float, low 10 mantissa bits = code index (K=1024).
__global__ __launch_bounds__(256, 2) void vq_main(const float* __restrict__ z,
                                                  const uint32_t* __restrict__ embf8,
                                                  const float* __restrict__ esqh,
                                                  float* __restrict__ out0,
                                                  float* __restrict__ lossp) {
    __shared__ __align__(16) unsigned char xsA[BM * 256];   // 16 KiB
    __shared__ __align__(16) unsigned char xsB[BM * 256];   // 16 KiB
    __shared__ float wvals[4][BM];
    __shared__ int   pidx[BM];
    __shared__ float zred[4];

    int tid  = threadIdx.x;
    int lane = tid & 63, w = tid >> 6;
    int ml   = lane & 15, quad = lane >> 4;
    int ph   = w >> 1, ch = w & 1;
    int blk  = blockIdx.x;
    int b    = blk >> 5;                      // 32 double-tiles per image
    int t0   = (blk & 31) * (2 * BM);
    const float* zbA = z + (size_t)b * (D_ * T_) + t0;
    const float* zbB = zbA + BM;
    float* obA = out0 + (size_t)b * (D_ * T_) + t0;
    float* obB = obA + BM;

    // ---- Phase 1(A): load z, NEGATED fp8-convert, transposed+swizzled store ----
    float zsqA = 0.f, zsqB = 0.f;
    {
        int t = lane, hf = (t >> 4) & 1;
        #pragma unroll 2
        for (int j = 0; j < 8; ++j) {
            int dgrp = w + 4 * j;
            int d0 = dgrp * 8;
            float f0 = zbA[(d0 + 0) * T_ + t];
            float f1 = zbA[(d0 + 1) * T_ + t];
            float f2 = zbA[(d0 + 2) * T_ + t];
            float f3 = zbA[(d0 + 3) * T_ + t];
            float f4 = zbA[(d0 + 4) * T_ + t];
            float f5 = zbA[(d0 + 5) * T_ + t];
            float f6 = zbA[(d0 + 6) * T_ + t];
            float f7 = zbA[(d0 + 7) * T_ + t];
            zsqA += f0*f0 + f1*f1 + f2*f2 + f3*f3 + f4*f4 + f5*f5 + f6*f6 + f7*f7;
            uint32_t p0 = (uint32_t)__builtin_amdgcn_cvt_pk_fp8_f32(-f0, -f1, 0, false);
            p0 = (uint32_t)__builtin_amdgcn_cvt_pk_fp8_f32(-f2, -f3, (int)p0, true);
            uint32_t p1 = (uint32_t)__builtin_amdgcn_cvt_pk_fp8_f32(-f4, -f5, 0, false);
            p1 = (uint32_t)__builtin_amdgcn_cvt_pk_fp8_f32(-f6, -f7, (int)p1, true);
            int c = dgrp >> 1, h = dgrp & 1;
            *(uint2*)&xsA[t * 256 + ((c ^ (t & 15)) << 4) + ((h ^ hf) << 3)] =
                make_uint2(p0, p1);
        }
    }

    int ct0 = ch * 32;                        // this wave's 32-tile code half
    const char* ebL = (const char*)embf8 + (size_t)ct0 * 4096 + (size_t)lane * 16;
    longx2 qq0[4], qq1[4];
    float eh0, eh1;
    const floatx4 zv = {0.f, 0.f, 0.f, 0.f};
    const unsigned hi_mask = 0xFFFFFC00u;

#define VQ_PREFETCH(QQ, EH, J)                                                  \
    {                                                                           \
        const char* p_ = ebL + (size_t)(J) * 4096;                              \
        _Pragma("unroll")                                                       \
        for (int i = 0; i < 4; ++i)                                             \
            QQ[i] = *(const longx2*)(p_ + i * 1024);                            \
        EH = esqh[(ct0 + (J)) * 16 + ml];                                       \
    }

// 16 MFMA, 4 chains (2 sets x lo/hi k-halves); lo chains start from C=ehv.
#define VQ_STEP(QQ, EH, J)                                                      \
    {                                                                           \
        floatx4 ehv = {EH, EH, EH, EH};                                         \
        floatx4 lo0, lo1, hi0, hi1;                                             \
        lo0 = __builtin_amdgcn_mfma_f32_16x16x32_fp8_fp8(afr[0][0], QQ[0][0], ehv, 0, 0, 0); \
        lo1 = __builtin_amdgcn_mfma_f32_16x16x32_fp8_fp8(afr[1][0], QQ[0][0], ehv, 0, 0, 0); \
        hi0 = __builtin_amdgcn_mfma_f32_16x16x32_fp8_fp8(afr[0][4], QQ[2][0], zv,  0, 0, 0); \
        hi1 = __builtin_amdgcn_mfma_f32_16x16x32_fp8_fp8(afr[1][4], QQ[2][0], zv,  0, 0, 0); \
        lo0 = __builtin_amdgcn_mfma_f32_16x16x32_fp8_fp8(afr[0][1], QQ[0][1], lo0, 0, 0, 0); \
        lo1 = __builtin_amdgcn_mfma_f32_16x16x32_fp8_fp8(afr[1][1], QQ[0][1], lo1, 0, 0, 0); \
        hi0 = __builtin_amdgcn_mfma_f32_16x16x32_fp8_fp8(afr[0][5], QQ[2][1], hi0, 0, 0, 0); \
        hi1 = __builtin_amdgcn_mfma_f32_16x16x32_fp8_fp8(afr[1][5], QQ[2][1], hi1, 0, 0, 0); \
        lo0 = __builtin_amdgcn_mfma_f32_16x16x32_fp8_fp8(afr[0][2], QQ[1][0], lo0, 0, 0, 0); \
        lo1 = __builtin_amdgcn_mfma_f32_16x16x32_fp8_fp8(afr[1][2], QQ[1][0], lo1, 0, 0, 0); \
        hi0 = __builtin_amdgcn_mfma_f32_16x16x32_fp8_fp8(afr[0][6], QQ[3][0], hi0, 0, 0, 0); \
        hi1 = __builtin_amdgcn_mfma_f32_16x16x32_fp8_fp8(afr[1][6], QQ[3][0], hi1, 0, 0, 0); \
        lo0 = __builtin_amdgcn_mfma_f32_16x16x32_fp8_fp8(afr[0][3], QQ[1][1], lo0, 0, 0, 0); \
        lo1 = __builtin_amdgcn_mfma_f32_16x16x32_fp8_fp8(afr[1][3], QQ[1][1], lo1, 0, 0, 0); \
        hi0 = __builtin_amdgcn_mfma_f32_16x16x32_fp8_fp8(afr[0][7], QQ[3][1], hi0, 0, 0, 0); \
        hi1 = __builtin_amdgcn_mfma_f32_16x16x32_fp8_fp8(afr[1][7], QQ[3][1], hi1, 0, 0, 0); \
        unsigned cbits = (unsigned)((ct0 + (J)) * 16 + ml);                     \
        _Pragma("unroll")                                                       \
        for (int i = 0; i < 4; ++i) {                                           \
            float d0 = lo0[i] + hi0[i];                                         \
            bv[0][i] = fminf(bv[0][i], __uint_as_float((__float_as_uint(d0) & hi_mask) | cbits)); \
            float d1 = lo1[i] + hi1[i];                                         \
            bv[1][i] = fminf(bv[1][i], __uint_as_float((__float_as_uint(d1) & hi_mask) | cbits)); \
        }                                                                       \
    }

#define VQ_K2(J)                                                                \
    VQ_PREFETCH(qq1, eh1, (J) + 1)                                              \
    VQ_STEP(qq0, eh0, (J))                                                      \
    if ((J) + 2 < 32) VQ_PREFETCH(qq0, eh0, (J) + 2)                            \
    VQ_STEP(qq1, eh1, (J) + 1)

    // prefetch tile j=0 (independent of xs; hides under barrier)
    VQ_PREFETCH(qq0, eh0, 0)
    __syncthreads();

    // ---- A-fragments for tile A ----
    long afr[2][8];
    #pragma unroll
    for (int ss = 0; ss < 2; ++ss) {
        int s = 2 * ph + ss;
        int pnt = s * 16 + ml;
        #pragma unroll
        for (int kk = 0; kk < 8; ++kk) {
            int c = 2 * kk + (quad >> 1), h = quad & 1;
            afr[ss][kk] = *(const long*)&xsA[pnt * 256 + ((c ^ ml) << 4) + ((h ^ (s & 1)) << 3)];
        }
    }

    float bv[2][4];
    #pragma unroll
    for (int ss = 0; ss < 2; ++ss)
        #pragma unroll
        for (int i = 0; i < 4; ++i) bv[ss][i] = 1e30f;

    // ---- k-loop(A) with interleaved P1(B): one z-chunk per 4 k-iters ----
    #pragma unroll 1
    for (int jj = 0; jj < 8; ++jj) {
        int j = 4 * jj;
        int t = lane, hf = (t >> 4) & 1;
        int dgrp = w + 4 * jj, d0 = dgrp * 8;
        VQ_PREFETCH(qq1, eh1, j + 1)
        // issue tile-B z loads (HBM) AFTER the qq prefetch: consuming qq
        // later waits with counted vmcnt, never drains these
        float f0 = zbB[(d0 + 0) * T_ + t];
        float f1 = zbB[(d0 + 1) * T_ + t];
        float f2 = zbB[(d0 + 2) * T_ + t];
        float f3 = zbB[(d0 + 3) * T_ + t];
        float f4 = zbB[(d0 + 4) * T_ + t];
        float f5 = zbB[(d0 + 5) * T_ + t];
        float f6 = zbB[(d0 + 6) * T_ + t];
        float f7 = zbB[(d0 + 7) * T_ + t];
        VQ_STEP(qq0, eh0, j)
        VQ_PREFETCH(qq0, eh0, j + 2)
        VQ_STEP(qq1, eh1, j + 1)
        // convert+store the chunk (z loads have had 2 STEPs of cover)
        zsqB += f0*f0 + f1*f1 + f2*f2 + f3*f3 + f4*f4 + f5*f5 + f6*f6 + f7*f7;
        {
            uint32_t p0 = (uint32_t)__builtin_amdgcn_cvt_pk_fp8_f32(-f0, -f1, 0, false);
            p0 = (uint32_t)__builtin_amdgcn_cvt_pk_fp8_f32(-f2, -f3, (int)p0, true);
            uint32_t p1 = (uint32_t)__builtin_amdgcn_cvt_pk_fp8_f32(-f4, -f5, 0, false);
            p1 = (uint32_t)__builtin_amdgcn_cvt_pk_fp8_f32(-f6, -f7, (int)p1, true);
            int c = dgrp >> 1, h = dgrp & 1;
            *(uint2*)&xsB[t * 256 + ((c ^ (t & 15)) << 4) + ((h ^ hf) << 3)] =
                make_uint2(p0, p1);
        }
        VQ_PREFETCH(qq1, eh1, j + 3)
        VQ_STEP(qq0, eh0, j + 2)
        if (j + 4 < 32) VQ_PREFETCH(qq0, eh0, j + 4)
        VQ_STEP(qq1, eh1, j + 3)
    }

    // ---- publish(A): per-wave min over 16 code-lanes ----
    #pragma unroll
    for (int ss = 0; ss < 2; ++ss)
        #pragma unroll
        for (int i = 0; i < 4; ++i) {
            float v = bv[ss][i];
            #pragma unroll
            for (int off = 1; off < 16; off <<= 1)
                v = fminf(v, __shfl_xor(v, off, 64));
            if (ml == 0) wvals[w][(2 * ph + ss) * 16 + quad * 4 + i] = v;
        }
    #pragma unroll
    for (int off = 32; off; off >>= 1) zsqA += __shfl_xor(zsqA, off, 64);
    if (lane == 0) zred[w] = zsqA;
    __syncthreads();

    // ---- merge(A) + loss ----
    if (tid < 64) {
        int t = tid, qb = (t >> 5) * 2;
        float wv = fminf(wvals[qb][t], wvals[qb + 1][t]);
        pidx[t] = (int)(__float_as_uint(wv) & 1023u);
        float lsum = wv;
        #pragma unroll
        for (int off = 32; off; off >>= 1) lsum += __shfl_xor(lsum, off, 64);
        if (t == 0) {
            float tot = zred[0] + zred[1] + zred[2] + zred[3] + lsum * (2.0f / 1024.f);
            atomicAdd(lossp, tot * (1.25f / 16777216.0f));   // 1.25/(N*D)
        }
    }
    __syncthreads();

    // ---- A-fragments for tile B; re-init bv ----
    #pragma unroll
    for (int ss = 0; ss < 2; ++ss) {
        int s = 2 * ph + ss;
        int pnt = s * 16 + ml;
        #pragma unroll
        for (int kk = 0; kk < 8; ++kk) {
            int c = 2 * kk + (quad >> 1), h = quad & 1;
            afr[ss][kk] = *(const long*)&xsB[pnt * 256 + ((c ^ ml) << 4) + ((h ^ (s & 1)) << 3)];
        }
    }
    #pragma unroll
    for (int ss = 0; ss < 2; ++ss)
        #pragma unroll
        for (int i = 0; i < 4; ++i) bv[ss][i] = 1e30f;

    VQ_PREFETCH(qq0, eh0, 0)

    // ---- issue P4a(A) gather loads (pidx valid; L2-resident rows) ----
    uint4 g0, g1, g2, g3;
    {
        int trow = tid >> 4, gcol = tid & 15;
        int base = (gcol >> 2) * 1024 + (gcol & 3) * 16 * 16;
        int c0 = pidx[trow +  0];
        int c1 = pidx[trow + 16];
        int c2 = pidx[trow + 32];
        int c3 = pidx[trow + 48];
        const char* eb = (const char*)embf8;
        g0 = *(const uint4*)(eb + (size_t)(c0 >> 4) * 4096 + base + (c0 & 15) * 16);
        g1 = *(const uint4*)(eb + (size_t)(c1 >> 4) * 4096 + base + (c1 & 15) * 16);
        g2 = *(const uint4*)(eb + (size_t)(c2 >> 4) * 4096 + base + (c2 & 15) * 16);
        g3 = *(const uint4*)(eb + (size_t)(c3 >> 4) * 4096 + base + (c3 & 15) * 16);
    }

    // ---- k-loop(B) iters 0..7 ----
    VQ_K2(0) VQ_K2(2) VQ_K2(4) VQ_K2(6)

    // ---- P4a(A): transpose gathered rows into xsA ----
    {
        int trow = tid >> 4, gcol = tid & 15;
        int col = (gcol ^ trow) << 4;      // (t&15)==trow for all 4 rows
        *(uint4*)&xsA[(trow +  0) * 256 + col] = g0;
        *(uint4*)&xsA[(trow + 16) * 256 + col] = g1;
        *(uint4*)&xsA[(trow + 32) * 256 + col] = g2;
        *(uint4*)&xsA[(trow + 48) * 256 + col] = g3;
    }
    __syncthreads();

    // ---- k-loop(B) iters 8..15 ----
    VQ_K2(8) VQ_K2(10) VQ_K2(12) VQ_K2(14)

    // ---- P4b(A): dequant + transpose-write; stores drain under iters 16..31 ----
    {
        int t = lane;
        #pragma unroll
        for (int jj = 0; jj < 4; ++jj) {
            int g = w + 4 * jj;
            uint4 v = *(const uint4*)&xsA[t * 256 + ((g ^ (t & 15)) << 4)];
            uint32_t wd[4] = {v.x, v.y, v.z, v.w};
            #pragma unroll
            for (int u = 0; u < 4; ++u) {
                int kk = (g >> 2) * 2 + (u >> 1);
                int d0 = kk * 32 + (g & 3) * 8 + (u & 1) * 4;
                floatx2 lo = __builtin_amdgcn_cvt_pk_f32_fp8((int)wd[u], false);
                floatx2 hi = __builtin_amdgcn_cvt_pk_f32_fp8((int)wd[u], true);
                obA[(d0 + 0) * T_ + t] = lo[0] * (1.f / 1024.f);
                obA[(d0 + 1) * T_ + t] = lo[1] * (1.f / 1024.f);
                obA[(d0 + 2) * T_ + t] = hi[0] * (1.f / 1024.f);
                obA[(d0 + 3) * T_ + t] = hi[1] * (1.f / 1024.f);
            }
        }
    }

    // ---- k-loop(B) iters 16..31 ----
    VQ_K2(16) VQ_K2(18) VQ_K2(20) VQ_K2(22)
    VQ_K2(24) VQ_K2(26) VQ_K2(28) VQ_K2(30)

#undef VQ_K2
#undef VQ_PREFETCH
#undef VQ_STEP

    // ---- publish(B) ----
    #pragma unroll
    for (int ss = 0; ss < 2; ++ss)
        #pragma unroll
        for (int i = 0; i < 4; ++i) {
            float v = bv[ss][i];
            #pragma unroll
            for (int off = 1; off < 16; off <<= 1)
                v = fminf(v, __shfl_xor(v, off, 64));
            if (ml == 0) wvals[w][(2 * ph + ss) * 16 + quad * 4 + i] = v;
        }
    #pragma unroll
    for (int off = 32; off; off >>= 1) zsqB += __shfl_xor(zsqB, off, 64);
    if (lane == 0) zred[w] = zsqB;
    __syncthreads();

    // ---- merge(B) + loss ----
    if (tid < 64) {
        int t = tid, qb = (t >> 5) * 2;
        float wv = fminf(wvals[qb][t], wvals[qb + 1][t]);
        pidx[t] = (int)(__float_as_uint(wv) & 1023u);
        float lsum = wv;
        #pragma unroll
        for (int off = 32; off; off >>= 1) lsum += __shfl_xor(lsum, off, 64);
        if (t == 0) {
            float tot = zred[0] + zred[1] + zred[2] + zred[3] + lsum * (2.0f / 1024.f);
            atomicAdd(lossp, tot * (1.25f / 16777216.0f));   // 1.25/(N*D)
        }
    }
    __syncthreads();

    // ---- P4a(B): gather winning rows into xsB ----
    #pragma unroll
    for (int m = 0; m < 4; ++m) {
        int t = (tid >> 4) + 16 * m;
        int g = tid & 15;
        int code = pidx[t];
        const char* src = (const char*)embf8 + (size_t)(code >> 4) * 4096
                        + (g >> 2) * 1024 + ((g & 3) * 16 + (code & 15)) * 16;
        uint4 v = *(const uint4*)src;
        *(uint4*)&xsB[t * 256 + ((g ^ (t & 15)) << 4)] = v;
    }
    __syncthreads();

    // ---- P4b(B): dequant + transpose-write ----
    {
        int t = lane;
        #pragma unroll
        for (int jj = 0; jj < 4; ++jj) {
            int g = w + 4 * jj;
            uint4 v = *(const uint4*)&xsB[t * 256 + ((g ^ (t & 15)) << 4)];
            uint32_t wd[4] = {v.x, v.y, v.z, v.w};
            #pragma unroll
            for (int u = 0; u < 4; ++u) {
                int kk = (g >> 2) * 2 + (u >> 1);
                int d0 = kk * 32 + (g & 3) * 8 + (u & 1) * 4;
                floatx2 lo = __builtin_amdgcn_cvt_pk_f32_fp8((int)wd[u], false);
                floatx2 hi = __builtin_amdgcn_cvt_pk_f32_fp8((int)wd[u], true);
                obB[(d0 + 0) * T_ + t] = lo[0] * (1.f / 1024.f);
                obB[(d0 + 1) * T_ + t] = lo[1] * (1.f / 1024.f);
                obB[(d0 + 2) * T_ + t] = hi[0] * (1.f / 1024.f);
                obB[(d0 + 3) * T_ + t] = hi[1] * (1.f / 1024.f);
            }
        }
    }
}

extern "C" void kernel_launch(void* const* d_in, const int* in_sizes, int n_in,
                              void* d_out, int out_size, void* d_ws, size_t ws_size,
                              hipStream_t stream) {
    (void)in_sizes; (void)n_in; (void)out_size; (void)ws_size;
    const float* z   = (const float*)d_in[0];
    const float* emb = (const float*)d_in[1];

    uint32_t* embf8 = (uint32_t*)d_ws;                              // 256 KiB
    float*    esqh  = (float*)((char*)d_ws + (size_t)K_ * D_);      // 4 KiB

    float* out0  = (float*)d_out;
    float* lossp = out0 + (size_t)N_ * D_;

    emb_prep<<<K_ / 4, 256, 0, stream>>>(emb, embf8, esqh, lossp);
    vq_main<<<N_ / (2 * BM), 256, 0, stream>>>(z, embf8, esqh, out0, lossp);
}

// Round 6
// 137.210 us; speedup vs baseline: 1.9592x; 1.9592x over previous
//
#include <hip/hip_runtime.h>
#include <stdint.h>

// Problem constants
#define B_   16
#define D_   256
#define T_   4096
#define K_   1024
#define N_   (B_ * T_)      // 65536 points
#define BM   64             // points per sub-tile; each block does TWO sub-tiles

typedef __attribute__((ext_vector_type(4))) float floatx4;
typedef __attribute__((ext_vector_type(2))) float floatx2;
typedef __attribute__((ext_vector_type(2))) long longx2;

// ---- Kernel 0: emb fp32 -> fp8 e4m3 (scaled x1024), stored in PIECE order:
// tile ct = codes [ct*16, ct*16+16), 4 KB = 4 pieces of 1 KB. Byte for
// (code c, dim d): ct=c>>4, ml=c&15, kk=d>>5, quad=(d>>3)&3, b=d&7 at
//   ct*4096 + (kk>>1)*1024 + (quad*16+ml)*16 + (kk&1)*8 + b
// esqh[c] = 1024*0.5*||e_exact||^2. Also zeroes loss.
__global__ __launch_bounds__(256) void emb_prep(const float* __restrict__ emb,
                                                uint32_t* __restrict__ embf8,
                                                float* __restrict__ esqh,
                                                float* __restrict__ lossp) {
    int w = threadIdx.x >> 6, lane = threadIdx.x & 63;
    int k = blockIdx.x * 4 + w;                       // one wave per code row
    float4 v = ((const float4*)emb)[k * 64 + lane];   // d0 = lane*4
    float a0 = v.x * 1024.f, a1 = v.y * 1024.f, a2 = v.z * 1024.f, a3 = v.w * 1024.f;
    int p = __builtin_amdgcn_cvt_pk_fp8_f32(a0, a1, 0, false);
    p = __builtin_amdgcn_cvt_pk_fp8_f32(a2, a3, p, true);
    int kk = lane >> 3, quad = (lane >> 1) & 3;       // from d0 = lane*4
    int widx = (k >> 4) * 1024 + (kk >> 1) * 256 + (quad * 16 + (k & 15)) * 4
             + (kk & 1) * 2 + (lane & 1);
    embf8[widx] = (uint32_t)p;
    float ss = a0 * a0 + a1 * a1 + a2 * a2 + a3 * a3;   // exact (pre-fp8) scaled norm
    #pragma unroll
    for (int off = 32; off; off >>= 1) ss += __shfl_xor(ss, off, 64);
    if (lane == 0) esqh[k] = ss * (0.5f / 1024.f);      // = 1024 * 0.5*||e||^2
    if (blockIdx.x == 0 && threadIdx.x == 0) *lossp = 0.f;
}

// ---- Main kernel (R6: R4 + minimal spill-proof 2-tile overlap) ----
// R5 post-mortem: 16 unrolled VQ_K2 (256 flat MFMAs) + long-lived gather/z
// regs -> spill (FETCH 191MB, WRITE 238MB, MfmaUtil 7%). R6 keeps R4's
// proven per-tile code EXACTLY and adds overlap with bounded live ranges:
//  - block does tiles A,B (grid 512, 2 blocks/CU, launch_bounds(256,3):
//    combined cap ~170 vs ~140 peak demand -> no spill).
//  - k-loop(A) rolled (#pragma unroll 1), first 8 bodies each carry ONE
//    z-chunk of tile B (8 loads at top, convert+ds_write at bottom; 8
//    transient regs, 2 STEPs of latency cover). HBM reads hide under MFMA.
//  - k-loop(B) rolled, first 4 double-bodies each carry ONE dequant/store
//    group of tile A -> the 64KB store burst drains under MFMAs.
//  - gather(A) is a compact pre-loop block (L2-resident, cheap).
// Exposed serial memory: P1(A) + gather/dequant(B) tail only.
// Wave decomposition per tile (R4): wave w = point-half ph=w>>1 x code-half
// ch=w&1; 32 tiles x 16 MFMA, 4 chains via k-split lo/hi; eh folded into
// lo-chain C operand; A holds NEGATED z fp8 so acc = eh - x.e.
// Argmin: packed float, low 10 mantissa bits = code index (K=1024).
__global__ __launch_bounds__(256, 3) void vq_main(const float* __restrict__ z,
                                                  const uint32_t* __restrict__ embf8,
                                                  const float* __restrict__ esqh,
                                                  float* __restrict__ out0,
                                                  float* __restrict__ lossp) {
    __shared__ __align__(16) unsigned char xsA[BM * 256];   // 16 KiB
    __shared__ __align__(16) unsigned char xsB[BM * 256];   // 16 KiB
    __shared__ float wvals[4][BM];
    __shared__ int   pidx[BM];
    __shared__ float zred[4];

    int tid  = threadIdx.x;
    int lane = tid & 63, w = tid >> 6;
    int ml   = lane & 15, quad = lane >> 4;
    int ph   = w >> 1, ch = w & 1;
    int blk  = blockIdx.x;
    int b    = blk >> 5;                      // 32 double-tiles per image
    int t0   = (blk & 31) * (2 * BM);
    const float* zbA = z + (size_t)b * (D_ * T_) + t0;
    const float* zbB = zbA + BM;
    float* obA = out0 + (size_t)b * (D_ * T_) + t0;
    float* obB = obA + BM;

    // ---- Phase 1(A): load z, NEGATED fp8-convert, transposed+swizzled store ----
    float zsqA = 0.f, zsqB = 0.f;
    {
        int t = lane, hf = (t >> 4) & 1;
        #pragma unroll 2
        for (int j = 0; j < 8; ++j) {
            int dgrp = w + 4 * j;
            int d0 = dgrp * 8;
            float f0 = zbA[(d0 + 0) * T_ + t];
            float f1 = zbA[(d0 + 1) * T_ + t];
            float f2 = zbA[(d0 + 2) * T_ + t];
            float f3 = zbA[(d0 + 3) * T_ + t];
            float f4 = zbA[(d0 + 4) * T_ + t];
            float f5 = zbA[(d0 + 5) * T_ + t];
            float f6 = zbA[(d0 + 6) * T_ + t];
            float f7 = zbA[(d0 + 7) * T_ + t];
            zsqA += f0*f0 + f1*f1 + f2*f2 + f3*f3 + f4*f4 + f5*f5 + f6*f6 + f7*f7;
            uint32_t p0 = (uint32_t)__builtin_amdgcn_cvt_pk_fp8_f32(-f0, -f1, 0, false);
            p0 = (uint32_t)__builtin_amdgcn_cvt_pk_fp8_f32(-f2, -f3, (int)p0, true);
            uint32_t p1 = (uint32_t)__builtin_amdgcn_cvt_pk_fp8_f32(-f4, -f5, 0, false);
            p1 = (uint32_t)__builtin_amdgcn_cvt_pk_fp8_f32(-f6, -f7, (int)p1, true);
            int c = dgrp >> 1, h = dgrp & 1;
            *(uint2*)&xsA[t * 256 + ((c ^ (t & 15)) << 4) + ((h ^ hf) << 3)] =
                make_uint2(p0, p1);
        }
    }

    int ct0 = ch * 32;                        // this wave's 32-tile code half
    const char* ebL = (const char*)embf8 + (size_t)ct0 * 4096 + (size_t)lane * 16;
    longx2 qq0[4], qq1[4];
    float eh0, eh1;
    const floatx4 zv = {0.f, 0.f, 0.f, 0.f};
    const unsigned hi_mask = 0xFFFFFC00u;

#define VQ_PREFETCH(QQ, EH, J)                                                  \
    {                                                                           \
        const char* p_ = ebL + (size_t)(J) * 4096;                              \
        _Pragma("unroll")                                                       \
        for (int i = 0; i < 4; ++i)                                             \
            QQ[i] = *(const longx2*)(p_ + i * 1024);                            \
        EH = esqh[(ct0 + (J)) * 16 + ml];                                       \
    }

// 16 MFMA, 4 chains (2 sets x lo/hi k-halves); lo chains start from C=ehv.
#define VQ_STEP(QQ, EH, J)                                                      \
    {                                                                           \
        floatx4 ehv = {EH, EH, EH, EH};                                         \
        floatx4 lo0, lo1, hi0, hi1;                                             \
        lo0 = __builtin_amdgcn_mfma_f32_16x16x32_fp8_fp8(afr[0][0], QQ[0][0], ehv, 0, 0, 0); \
        lo1 = __builtin_amdgcn_mfma_f32_16x16x32_fp8_fp8(afr[1][0], QQ[0][0], ehv, 0, 0, 0); \
        hi0 = __builtin_amdgcn_mfma_f32_16x16x32_fp8_fp8(afr[0][4], QQ[2][0], zv,  0, 0, 0); \
        hi1 = __builtin_amdgcn_mfma_f32_16x16x32_fp8_fp8(afr[1][4], QQ[2][0], zv,  0, 0, 0); \
        lo0 = __builtin_amdgcn_mfma_f32_16x16x32_fp8_fp8(afr[0][1], QQ[0][1], lo0, 0, 0, 0); \
        lo1 = __builtin_amdgcn_mfma_f32_16x16x32_fp8_fp8(afr[1][1], QQ[0][1], lo1, 0, 0, 0); \
        hi0 = __builtin_amdgcn_mfma_f32_16x16x32_fp8_fp8(afr[0][5], QQ[2][1], hi0, 0, 0, 0); \
        hi1 = __builtin_amdgcn_mfma_f32_16x16x32_fp8_fp8(afr[1][5], QQ[2][1], hi1, 0, 0, 0); \
        lo0 = __builtin_amdgcn_mfma_f32_16x16x32_fp8_fp8(afr[0][2], QQ[1][0], lo0, 0, 0, 0); \
        lo1 = __builtin_amdgcn_mfma_f32_16x16x32_fp8_fp8(afr[1][2], QQ[1][0], lo1, 0, 0, 0); \
        hi0 = __builtin_amdgcn_mfma_f32_16x16x32_fp8_fp8(afr[0][6], QQ[3][0], hi0, 0, 0, 0); \
        hi1 = __builtin_amdgcn_mfma_f32_16x16x32_fp8_fp8(afr[1][6], QQ[3][0], hi1, 0, 0, 0); \
        lo0 = __builtin_amdgcn_mfma_f32_16x16x32_fp8_fp8(afr[0][3], QQ[1][1], lo0, 0, 0, 0); \
        lo1 = __builtin_amdgcn_mfma_f32_16x16x32_fp8_fp8(afr[1][3], QQ[1][1], lo1, 0, 0, 0); \
        hi0 = __builtin_amdgcn_mfma_f32_16x16x32_fp8_fp8(afr[0][7], QQ[3][1], hi0, 0, 0, 0); \
        hi1 = __builtin_amdgcn_mfma_f32_16x16x32_fp8_fp8(afr[1][7], QQ[3][1], hi1, 0, 0, 0); \
        unsigned cbits = (unsigned)((ct0 + (J)) * 16 + ml);                     \
        _Pragma("unroll")                                                       \
        for (int i = 0; i < 4; ++i) {                                           \
            float d0 = lo0[i] + hi0[i];                                         \
            bv[0][i] = fminf(bv[0][i], __uint_as_float((__float_as_uint(d0) & hi_mask) | cbits)); \
            float d1 = lo1[i] + hi1[i];                                         \
            bv[1][i] = fminf(bv[1][i], __uint_as_float((__float_as_uint(d1) & hi_mask) | cbits)); \
        }                                                                       \
    }

    // prefetch tile j=0 (independent of xs; hides under barrier)
    VQ_PREFETCH(qq0, eh0, 0)
    __syncthreads();

    // ---- A-fragments for tile A ----
    long afr[2][8];
    #pragma unroll
    for (int ss = 0; ss < 2; ++ss) {
        int s = 2 * ph + ss;
        int pnt = s * 16 + ml;
        #pragma unroll
        for (int kk = 0; kk < 8; ++kk) {
            int c = 2 * kk + (quad >> 1), h = quad & 1;
            afr[ss][kk] = *(const long*)&xsA[pnt * 256 + ((c ^ ml) << 4) + ((h ^ (s & 1)) << 3)];
        }
    }

    float bv[2][4];
    #pragma unroll
    for (int ss = 0; ss < 2; ++ss)
        #pragma unroll
        for (int i = 0; i < 4; ++i) bv[ss][i] = 1e30f;

    // ---- k-loop(A) part 1: bodies carry one P1(B) z-chunk each ----
    #pragma unroll 1
    for (int jj = 0; jj < 8; ++jj) {
        int j = 2 * jj;
        VQ_PREFETCH(qq1, eh1, j + 1)
        // tile-B z loads (HBM), issued after the qq prefetch, consumed at
        // body end: ~2 STEPs of MFMA cover
        int t = lane, hf = (t >> 4) & 1;
        int dgrp = w + 4 * jj, d0 = dgrp * 8;
        float f0 = zbB[(d0 + 0) * T_ + t];
        float f1 = zbB[(d0 + 1) * T_ + t];
        float f2 = zbB[(d0 + 2) * T_ + t];
        float f3 = zbB[(d0 + 3) * T_ + t];
        float f4 = zbB[(d0 + 4) * T_ + t];
        float f5 = zbB[(d0 + 5) * T_ + t];
        float f6 = zbB[(d0 + 6) * T_ + t];
        float f7 = zbB[(d0 + 7) * T_ + t];
        VQ_STEP(qq0, eh0, j)
        VQ_PREFETCH(qq0, eh0, j + 2)
        VQ_STEP(qq1, eh1, j + 1)
        zsqB += f0*f0 + f1*f1 + f2*f2 + f3*f3 + f4*f4 + f5*f5 + f6*f6 + f7*f7;
        {
            uint32_t p0 = (uint32_t)__builtin_amdgcn_cvt_pk_fp8_f32(-f0, -f1, 0, false);
            p0 = (uint32_t)__builtin_amdgcn_cvt_pk_fp8_f32(-f2, -f3, (int)p0, true);
            uint32_t p1 = (uint32_t)__builtin_amdgcn_cvt_pk_fp8_f32(-f4, -f5, 0, false);
            p1 = (uint32_t)__builtin_amdgcn_cvt_pk_fp8_f32(-f6, -f7, (int)p1, true);
            int c = dgrp >> 1, h = dgrp & 1;
            *(uint2*)&xsB[t * 256 + ((c ^ (t & 15)) << 4) + ((h ^ hf) << 3)] =
                make_uint2(p0, p1);
        }
    }
    // ---- k-loop(A) part 2: plain ----
    #pragma unroll 1
    for (int jj = 8; jj < 16; ++jj) {
        int j = 2 * jj;
        VQ_PREFETCH(qq1, eh1, j + 1)
        VQ_STEP(qq0, eh0, j)
        if (j + 2 < 32) VQ_PREFETCH(qq0, eh0, j + 2)
        VQ_STEP(qq1, eh1, j + 1)
    }

    // ---- publish(A): per-wave min over 16 code-lanes ----
    #pragma unroll
    for (int ss = 0; ss < 2; ++ss)
        #pragma unroll
        for (int i = 0; i < 4; ++i) {
            float v = bv[ss][i];
            #pragma unroll
            for (int off = 1; off < 16; off <<= 1)
                v = fminf(v, __shfl_xor(v, off, 64));
            if (ml == 0) wvals[w][(2 * ph + ss) * 16 + quad * 4 + i] = v;
        }
    #pragma unroll
    for (int off = 32; off; off >>= 1) zsqA += __shfl_xor(zsqA, off, 64);
    if (lane == 0) zred[w] = zsqA;
    __syncthreads();

    // ---- merge(A) + loss ----
    if (tid < 64) {
        int t = tid, qb = (t >> 5) * 2;
        float wv = fminf(wvals[qb][t], wvals[qb + 1][t]);
        pidx[t] = (int)(__float_as_uint(wv) & 1023u);
        float lsum = wv;
        #pragma unroll
        for (int off = 32; off; off >>= 1) lsum += __shfl_xor(lsum, off, 64);
        if (t == 0) {
            float tot = zred[0] + zred[1] + zred[2] + zred[3] + lsum * (2.0f / 1024.f);
            atomicAdd(lossp, tot * (1.25f / 16777216.0f));   // 1.25/(N*D)
        }
    }
    __syncthreads();

    // ---- A-fragments for tile B (xsB complete since publish barrier) ----
    #pragma unroll
    for (int ss = 0; ss < 2; ++ss) {
        int s = 2 * ph + ss;
        int pnt = s * 16 + ml;
        #pragma unroll
        for (int kk = 0; kk < 8; ++kk) {
            int c = 2 * kk + (quad >> 1), h = quad & 1;
            afr[ss][kk] = *(const long*)&xsB[pnt * 256 + ((c ^ ml) << 4) + ((h ^ (s & 1)) << 3)];
        }
    }
    #pragma unroll
    for (int ss = 0; ss < 2; ++ss)
        #pragma unroll
        for (int i = 0; i < 4; ++i) bv[ss][i] = 1e30f;

    // ---- P4a(A): gather winning rows into xsA (compact, L2-resident) ----
    #pragma unroll
    for (int m = 0; m < 4; ++m) {
        int t = (tid >> 4) + 16 * m;
        int g = tid & 15;
        int code = pidx[t];
        const char* src = (const char*)embf8 + (size_t)(code >> 4) * 4096
                        + (g >> 2) * 1024 + ((g & 3) * 16 + (code & 15)) * 16;
        uint4 v = *(const uint4*)src;
        *(uint4*)&xsA[t * 256 + ((g ^ (t & 15)) << 4)] = v;
    }
    VQ_PREFETCH(qq0, eh0, 0)
    __syncthreads();

    // ---- k-loop(B) part 1: double-bodies carry one P4b(A) dequant group ----
    #pragma unroll 1
    for (int jj = 0; jj < 4; ++jj) {
        int j = 4 * jj;
        VQ_PREFETCH(qq1, eh1, j + 1)
        VQ_STEP(qq0, eh0, j)
        VQ_PREFETCH(qq0, eh0, j + 2)
        VQ_STEP(qq1, eh1, j + 1)
        // dequant group jj of tile A: stores drain under following MFMAs
        {
            int t = lane;
            int g = w + 4 * jj;
            uint4 v = *(const uint4*)&xsA[t * 256 + ((g ^ (t & 15)) << 4)];
            uint32_t wd[4] = {v.x, v.y, v.z, v.w};
            #pragma unroll
            for (int u = 0; u < 4; ++u) {
                int kk = (g >> 2) * 2 + (u >> 1);
                int d0 = kk * 32 + (g & 3) * 8 + (u & 1) * 4;
                floatx2 lo = __builtin_amdgcn_cvt_pk_f32_fp8((int)wd[u], false);
                floatx2 hi = __builtin_amdgcn_cvt_pk_f32_fp8((int)wd[u], true);
                obA[(d0 + 0) * T_ + t] = lo[0] * (1.f / 1024.f);
                obA[(d0 + 1) * T_ + t] = lo[1] * (1.f / 1024.f);
                obA[(d0 + 2) * T_ + t] = hi[0] * (1.f / 1024.f);
                obA[(d0 + 3) * T_ + t] = hi[1] * (1.f / 1024.f);
            }
        }
        VQ_PREFETCH(qq1, eh1, j + 3)
        VQ_STEP(qq0, eh0, j + 2)
        VQ_PREFETCH(qq0, eh0, j + 4)
        VQ_STEP(qq1, eh1, j + 3)
    }
    // ---- k-loop(B) part 2: plain ----
    #pragma unroll 1
    for (int jj = 8; jj < 16; ++jj) {
        int j = 2 * jj;
        VQ_PREFETCH(qq1, eh1, j + 1)
        VQ_STEP(qq0, eh0, j)
        if (j + 2 < 32) VQ_PREFETCH(qq0, eh0, j + 2)
        VQ_STEP(qq1, eh1, j + 1)
    }

#undef VQ_PREFETCH
#undef VQ_STEP

    // ---- publish(B) ----
    #pragma unroll
    for (int ss = 0; ss < 2; ++ss)
        #pragma unroll
        for (int i = 0; i < 4; ++i) {
            float v = bv[ss][i];
            #pragma unroll
            for (int off = 1; off < 16; off <<= 1)
                v = fminf(v, __shfl_xor(v, off, 64));
            if (ml == 0) wvals[w][(2 * ph + ss) * 16 + quad * 4 + i] = v;
        }
    #pragma unroll
    for (int off = 32; off; off >>= 1) zsqB += __shfl_xor(zsqB, off, 64);
    if (lane == 0) zred[w] = zsqB;
    __syncthreads();

    // ---- merge(B) + loss ----
    if (tid < 64) {
        int t = tid, qb = (t >> 5) * 2;
        float wv = fminf(wvals[qb][t], wvals[qb + 1][t]);
        pidx[t] = (int)(__float_as_uint(wv) & 1023u);
        float lsum = wv;
        #pragma unroll
        for (int off = 32; off; off >>= 1) lsum += __shfl_xor(lsum, off, 64);
        if (t == 0) {
            float tot = zred[0] + zred[1] + zred[2] + zred[3] + lsum * (2.0f / 1024.f);
            atomicAdd(lossp, tot * (1.25f / 16777216.0f));   // 1.25/(N*D)
        }
    }
    __syncthreads();

    // ---- P4a(B): gather winning rows into xsB (xsB free: afr consumed) ----
    #pragma unroll
    for (int m = 0; m < 4; ++m) {
        int t = (tid >> 4) + 16 * m;
        int g = tid & 15;
        int code = pidx[t];
        const char* src = (const char*)embf8 + (size_t)(code >> 4) * 4096
                        + (g >> 2) * 1024 + ((g & 3) * 16 + (code & 15)) * 16;
        uint4 v = *(const uint4*)src;
        *(uint4*)&xsB[t * 256 + ((g ^ (t & 15)) << 4)] = v;
    }
    __syncthreads();

    // ---- P4b(B): dequant + transpose-write ----
    {
        int t = lane;
        #pragma unroll
        for (int jj = 0; jj < 4; ++jj) {
            int g = w + 4 * jj;
            uint4 v = *(const uint4*)&xsB[t * 256 + ((g ^ (t & 15)) << 4)];
            uint32_t wd[4] = {v.x, v.y, v.z, v.w};
            #pragma unroll
            for (int u = 0; u < 4; ++u) {
                int kk = (g >> 2) * 2 + (u >> 1);
                int d0 = kk * 32 + (g & 3) * 8 + (u & 1) * 4;
                floatx2 lo = __builtin_amdgcn_cvt_pk_f32_fp8((int)wd[u], false);
                floatx2 hi = __builtin_amdgcn_cvt_pk_f32_fp8((int)wd[u], true);
                obB[(d0 + 0) * T_ + t] = lo[0] * (1.f / 1024.f);
                obB[(d0 + 1) * T_ + t] = lo[1] * (1.f / 1024.f);
                obB[(d0 + 2) * T_ + t] = hi[0] * (1.f / 1024.f);
                obB[(d0 + 3) * T_ + t] = hi[1] * (1.f / 1024.f);
            }
        }
    }
}

extern "C" void kernel_launch(void* const* d_in, const int* in_sizes, int n_in,
                              void* d_out, int out_size, void* d_ws, size_t ws_size,
                              hipStream_t stream) {
    (void)in_sizes; (void)n_in; (void)out_size; (void)ws_size;
    const float* z   = (const float*)d_in[0];
    const float* emb = (const float*)d_in[1];

    uint32_t* embf8 = (uint32_t*)d_ws;                              // 256 KiB
    float*    esqh  = (float*)((char*)d_ws + (size_t)K_ * D_);      // 4 KiB

    float* out0  = (float*)d_out;
    float* lossp = out0 + (size_t)N_ * D_;

    emb_prep<<<K_ / 4, 256, 0, stream>>>(emb, embf8, esqh, lossp);
    vq_main<<<N_ / (2 * BM), 256, 0, stream>>>(z, embf8, esqh, out0, lossp);
}